// Round 1
// 138.280 us; speedup vs baseline: 1.0109x; 1.0109x over previous
//
#include <hip/hip_runtime.h>

// Problem constants (from reference): B=64, OH=120, OW=160, THRESHOLD=0.5
#define OW_   160
#define OH_   120
#define HW_   (OH_ * OW_)          // 19200
#define BATCH 64
#define NPIX  (BATCH * HW_)        // 1228800
#define BLK   256
#define PPT   2                    // pixels per thread
#define PPB   (BLK * PPT)          // 512 pixels per block; pairs never span a batch (HW_ even)

// Output layout in d_out (flat, return order):
//   boxes     [NPIX*5]   at offset 0
//   landmarks [NPIX*10]  at offset NPIX*5
//   keep      [NPIX]     at offset NPIX*15
#define BOX_OFF 0
#define LM_OFF  ((size_t)NPIX * 5)
#define KEEP_OFF ((size_t)NPIX * 15)

typedef float f2v __attribute__((ext_vector_type(2)));
typedef float f4v __attribute__((ext_vector_type(4)));

__global__ __launch_bounds__(BLK) void detpost_kernel(
    const float* __restrict__ heatmap,   // [B,1,H,W]
    const float* __restrict__ scale,     // [B,2,H,W]
    const float* __restrict__ offset,    // [B,2,H,W]
    const float* __restrict__ landmark,  // [B,10,H,W]
    float* __restrict__ boxes,           // [B*HW,5]
    float* __restrict__ lms,             // [B*HW,10]
    float* __restrict__ keepo)           // [B*HW]
{
    __shared__ float sbox[PPB * 5];      // 10 KB
    __shared__ float slm [PPB * 10];     // 20 KB   (30 KB total -> 5 blocks/CU, 20 waves/CU)

    const int tid  = threadIdx.x;
    const int gp   = blockIdx.x * BLK + tid;   // global pixel-pair index
    const int base = gp * 2;                   // first pixel of the pair
    const int b    = base / HW_;               // pair never crosses batch (HW_ even)
    const int p    = base - b * HW_;
    const int h    = p / OW_;                  // both pixels share a row (OW_ even)

    // ---- coalesced float2 channel-planar loads (8 B/lane) ----
    const f2v hm   = *(const f2v*)(heatmap + base);
    const float* scb = scale + (size_t)b * 2 * HW_;
    const f2v sc0v = *(const f2v*)(scb + p);
    const f2v sc1v = *(const f2v*)(scb + HW_ + p);
    const f2v of0v = *(const f2v*)(offset + (size_t)b * 2 * HW_ + p);  // channel 1 unused by reference

    const float* lmb = landmark + (size_t)b * 10 * HW_ + p;
    f2v lmv[10];
#pragma unroll
    for (int c = 0; c < 10; ++c) lmv[c] = *(const f2v*)(lmb + (size_t)c * HW_);

    // ---- per-pixel math (fp32, matches reference incl. x1-from-y1c quirk) ----
    float s0a[2], s1a[2], y1a[2], x1a[2];
    bool  kp[2];
    f2v   kk;
#pragma unroll
    for (int q = 0; q < 2; ++q) {
        const float sc  = q ? hm.y   : hm.x;
        const float sc0 = q ? sc0v.y : sc0v.x;
        const float sc1 = q ? sc1v.y : sc1v.x;
        const float o0  = q ? of0v.y : of0v.x;

        const float s0 = __expf(sc0) * 4.0f;
        const float s1 = __expf(sc1) * 4.0f;
        const float y1raw = ((float)h + o0 + 0.5f) * 4.0f - s0 * 0.5f;
        const float y1c = fmaxf(y1raw, 0.0f);
        const float y1  = fminf(y1c, 480.0f);     // in_h = OH*4
        const float x1  = fminf(y1c, 640.0f);     // in_w = OW*4 (from y1c — reference quirk)
        const float y2  = fminf(y1 + s0, 480.0f);
        const float x2  = fminf(x1 + s1, 640.0f);
        const bool keep = (sc >= 0.5f);

        float* sb = sbox + (2 * tid + q) * 5;
        sb[0] = keep ? x1 : 0.0f;
        sb[1] = keep ? y1 : 0.0f;
        sb[2] = keep ? x2 : 0.0f;
        sb[3] = keep ? y2 : 0.0f;
        sb[4] = keep ? sc : 0.0f;

        s0a[q] = s0; s1a[q] = s1; y1a[q] = y1; x1a[q] = x1; kp[q] = keep;
        if (q == 0) kk.x = keep ? 1.0f : 0.0f; else kk.y = keep ? 1.0f : 0.0f;
    }

    // ---- landmarks: even channels use (s0,y1), odd use (s1,x1) ----
#pragma unroll
    for (int c = 0; c < 10; ++c) {
#pragma unroll
        for (int q = 0; q < 2; ++q) {
            const float lv = q ? lmv[c].y : lmv[c].x;
            const float v  = (c & 1) ? fmaf(lv, s1a[q], x1a[q]) : fmaf(lv, s0a[q], y1a[q]);
            slm[(2 * tid + q) * 10 + c] = kp[q] ? v : 0.0f;
        }
    }

    // keep mask: output-linear already; nontemporal float2 store
    __builtin_nontemporal_store(kk, (f2v*)(keepo + base));

    __syncthreads();

    // ---- coalesced nontemporal float4 stores from LDS (output-linear) ----
    // boxes: 512*5 = 2560 floats = 640 float4 per block
    {
        const f4v* sb4 = (const f4v*)sbox;
        f4v* gb4 = (f4v*)(boxes + (size_t)blockIdx.x * (PPB * 5));
#pragma unroll
        for (int j = tid; j < PPB * 5 / 4; j += BLK)
            __builtin_nontemporal_store(sb4[j], gb4 + j);
    }
    // landmarks: 512*10 = 5120 floats = 1280 float4 per block (5 full iters)
    {
        const f4v* sl4 = (const f4v*)slm;
        f4v* gl4 = (f4v*)(lms + (size_t)blockIdx.x * (PPB * 10));
#pragma unroll
        for (int j = tid; j < PPB * 10 / 4; j += BLK)
            __builtin_nontemporal_store(sl4[j], gl4 + j);
    }
}

extern "C" void kernel_launch(void* const* d_in, const int* in_sizes, int n_in,
                              void* d_out, int out_size, void* d_ws, size_t ws_size,
                              hipStream_t stream) {
    const float* heatmap  = (const float*)d_in[0];
    const float* scale    = (const float*)d_in[1];
    const float* offset   = (const float*)d_in[2];
    const float* landmark = (const float*)d_in[3];

    float* out   = (float*)d_out;
    float* boxes = out + BOX_OFF;
    float* lms   = out + LM_OFF;
    float* keepo = out + KEEP_OFF;

    const int nblocks = NPIX / PPB;   // 2400, exact
    detpost_kernel<<<nblocks, BLK, 0, stream>>>(heatmap, scale, offset, landmark,
                                                boxes, lms, keepo);
}